// Round 1
// baseline (417.705 us; speedup 1.0000x reference)
//
#include <hip/hip_runtime.h>
#include <math.h>

#define D 128

// ---------------- degree / normalization ----------------

__global__ void init_cnt(int* __restrict__ cnt, int n) {
    int i = blockIdx.x * blockDim.x + threadIdx.x;
    if (i < n) cnt[i] = 0;
}

__global__ void count_deg(const int* __restrict__ dst, int* __restrict__ cnt, int e) {
    int i = blockIdx.x * blockDim.x + threadIdx.x;
    if (i < e) atomicAdd(&cnt[dst[i]], 1);
}

__global__ void compute_dinv(const int* __restrict__ cnt, float* __restrict__ dinv, int n) {
    int i = blockIdx.x * blockDim.x + threadIdx.x;
    // self-loop => deg = indeg + 1 >= 1, rsqrt always valid
    if (i < n) dinv[i] = rsqrtf((float)(cnt[i] + 1));
}

// ---------------- CSR build (scan + fill) ----------------

// per-256-chunk inclusive scan -> exclusive within chunk, plus chunk totals
__global__ void scan_chunk(const int* __restrict__ cnt, int* __restrict__ rowStart,
                           int* __restrict__ chunkSum, int n) {
    __shared__ int sh[256];
    int tid = threadIdx.x;
    int i = blockIdx.x * 256 + tid;
    int v = (i < n) ? cnt[i] : 0;
    sh[tid] = v;
    __syncthreads();
    for (int o = 1; o < 256; o <<= 1) {
        int t = (tid >= o) ? sh[tid - o] : 0;
        __syncthreads();
        sh[tid] += t;
        __syncthreads();
    }
    if (i < n) rowStart[i] = sh[tid] - v;  // exclusive within chunk
    if (tid == 255) chunkSum[blockIdx.x] = sh[255];
}

// single-block scan of chunk totals (nb <= 256)
__global__ void scan_tops(const int* __restrict__ chunkSum, int* __restrict__ chunkOff, int nb) {
    __shared__ int sh[256];
    int tid = threadIdx.x;
    int v = (tid < nb) ? chunkSum[tid] : 0;
    sh[tid] = v;
    __syncthreads();
    for (int o = 1; o < 256; o <<= 1) {
        int t = (tid >= o) ? sh[tid - o] : 0;
        __syncthreads();
        sh[tid] += t;
        __syncthreads();
    }
    if (tid < nb) chunkOff[tid] = sh[tid] - v;  // exclusive
}

__global__ void finalize_scan(int* __restrict__ rowStart, int* __restrict__ cursor,
                              const int* __restrict__ chunkOff, int n, int e) {
    int i = blockIdx.x * blockDim.x + threadIdx.x;
    if (i < n) {
        int r = rowStart[i] + chunkOff[i >> 8];
        rowStart[i] = r;
        cursor[i] = r;
    }
    if (i == 0) rowStart[n] = e;
}

__global__ void fill_csr(const int* __restrict__ src, const int* __restrict__ dst,
                         const float* __restrict__ dinv, int* __restrict__ cursor,
                         int* __restrict__ col, float* __restrict__ w, int e) {
    int i = blockIdx.x * blockDim.x + threadIdx.x;
    if (i < e) {
        int s = src[i], dd = dst[i];
        int p = atomicAdd(&cursor[dd], 1);
        col[p] = s;
        w[p] = dinv[s] * dinv[dd];
    }
}

// ---------------- dense transform: C[N,128] = A[N,128] @ W[128,128] ----------------
// BM=64 rows/block, full 128 cols, BK=32 k-chunks. 256 threads, 8x4 micro-tile.

__global__ __launch_bounds__(256) void gemm_nd(const float* __restrict__ A,
                                               const float* __restrict__ Wm,
                                               float* __restrict__ C, int N) {
    __shared__ float As[32][68];   // [k][m], padded: 68*4=272B rows keep 16B align, break bank aliasing
    __shared__ float Bs[32][128];  // [k][n]

    const int tid = threadIdx.x;
    const int row0 = blockIdx.x * 64;
    const int tr = tid >> 5;          // 0..7 -> rows tr*8 .. tr*8+7
    const int tc = (tid & 31) << 2;   // col base, 4 cols

    float acc[8][4] = {};

    for (int k0 = 0; k0 < D; k0 += 32) {
        // stage A chunk (64x32), transposed into As[k][m]
#pragma unroll
        for (int i = 0; i < 2; ++i) {
            int idx = tid + i * 256;       // 0..511
            int m = idx >> 3;              // 0..63
            int kk = (idx & 7) << 2;       // 0..28
            float4 v = make_float4(0.f, 0.f, 0.f, 0.f);
            int gr = row0 + m;
            if (gr < N) v = *(const float4*)&A[(size_t)gr * D + k0 + kk];
            As[kk + 0][m] = v.x;
            As[kk + 1][m] = v.y;
            As[kk + 2][m] = v.z;
            As[kk + 3][m] = v.w;
        }
        // stage W chunk (32x128)
#pragma unroll
        for (int i = 0; i < 4; ++i) {
            int idx = tid + i * 256;       // 0..1023
            int k = idx >> 5;              // 0..31
            int n = (idx & 31) << 2;       // 0..124
            *(float4*)&Bs[k][n] = *(const float4*)&Wm[(size_t)(k0 + k) * D + n];
        }
        __syncthreads();

#pragma unroll
        for (int k = 0; k < 32; ++k) {
            float4 b = *(float4*)&Bs[k][tc];
            float4 a0 = *(float4*)&As[k][tr * 8];
            float4 a1 = *(float4*)&As[k][tr * 8 + 4];
            float a[8] = {a0.x, a0.y, a0.z, a0.w, a1.x, a1.y, a1.z, a1.w};
            float bb[4] = {b.x, b.y, b.z, b.w};
#pragma unroll
            for (int r = 0; r < 8; ++r)
#pragma unroll
                for (int c = 0; c < 4; ++c)
                    acc[r][c] = fmaf(a[r], bb[c], acc[r][c]);
        }
        __syncthreads();
    }

#pragma unroll
    for (int r = 0; r < 8; ++r) {
        int gr = row0 + tr * 8 + r;
        if (gr < N) {
            float4 v = make_float4(acc[r][0], acc[r][1], acc[r][2], acc[r][3]);
            *(float4*)&C[(size_t)gr * D + tc] = v;
        }
    }
}

// ---------------- neighbor aggregation + bias + ELU ----------------
// one 128-thread block per node; thread d handles channel d

__global__ __launch_bounds__(128) void agg_elu(const float* __restrict__ h,
                                               const int* __restrict__ rowStart,
                                               const int* __restrict__ col,
                                               const float* __restrict__ w,
                                               const float* __restrict__ dinv,
                                               const float* __restrict__ bias,
                                               float* __restrict__ out, int n) {
    int node = blockIdx.x;
    int d = threadIdx.x;
    float di = dinv[node];
    float acc = di * di * h[(size_t)node * D + d];   // self-loop term
    int s0 = rowStart[node], s1 = rowStart[node + 1];
    for (int i = s0; i < s1; ++i) {
        acc = fmaf(w[i], h[(size_t)col[i] * D + d], acc);
    }
    acc += bias[d];
    out[(size_t)node * D + d] = acc > 0.0f ? acc : expm1f(acc);
}

// ---------------- launch ----------------

extern "C" void kernel_launch(void* const* d_in, const int* in_sizes, int n_in,
                              void* d_out, int out_size, void* d_ws, size_t ws_size,
                              hipStream_t stream) {
    const float* x  = (const float*)d_in[0];
    const int*   ei = (const int*)d_in[1];
    const float* W1 = (const float*)d_in[2];
    const float* b1 = (const float*)d_in[3];
    const float* W2 = (const float*)d_in[4];
    const float* b2 = (const float*)d_in[5];
    float* out = (float*)d_out;

    const int N = in_sizes[0] / D;
    const int E = in_sizes[1] / 2;
    const int* src = ei;
    const int* dst = ei + E;

    char* ws = (char*)d_ws;
    size_t off = 0;
    auto alloc = [&](size_t bytes) -> void* {
        void* p = ws + off;
        off = (off + bytes + 255) & ~(size_t)255;
        return p;
    };
    int*   cnt      = (int*)alloc((size_t)N * 4);
    int*   rowStart = (int*)alloc((size_t)(N + 1) * 4);
    int*   cursor   = (int*)alloc((size_t)N * 4);
    float* dinv     = (float*)alloc((size_t)N * 4);
    int*   chunkSum = (int*)alloc(256 * 4);
    int*   chunkOff = (int*)alloc(256 * 4);
    int*   col      = (int*)alloc((size_t)E * 4);
    float* w        = (float*)alloc((size_t)E * 4);
    float* bufA     = (float*)alloc((size_t)N * D * 4);
    (void)ws_size; (void)n_in; (void)out_size;

    const int nb256 = (N + 255) / 256;
    const int eb256 = (E + 255) / 256;

    // build normalization + CSR (ws is poisoned each call -> rebuild everything)
    init_cnt<<<nb256, 256, 0, stream>>>(cnt, N);
    count_deg<<<eb256, 256, 0, stream>>>(dst, cnt, E);
    compute_dinv<<<nb256, 256, 0, stream>>>(cnt, dinv, N);
    scan_chunk<<<nb256, 256, 0, stream>>>(cnt, rowStart, chunkSum, N);
    scan_tops<<<1, 256, 0, stream>>>(chunkSum, chunkOff, nb256);
    finalize_scan<<<nb256, 256, 0, stream>>>(rowStart, cursor, chunkOff, N, E);
    fill_csr<<<eb256, 256, 0, stream>>>(src, dst, dinv, cursor, col, w, E);

    const int gemmBlocks = (N + 63) / 64;
    // layer 1: bufA = x @ W1 ; out = ELU(Agg(bufA) + b1)
    gemm_nd<<<gemmBlocks, 256, 0, stream>>>(x, W1, bufA, N);
    agg_elu<<<N, 128, 0, stream>>>(bufA, rowStart, col, w, dinv, b1, out, N);
    // layer 2: bufA = out @ W2 ; out = ELU(Agg(bufA) + b2)
    gemm_nd<<<gemmBlocks, 256, 0, stream>>>(out, W2, bufA, N);
    agg_elu<<<N, 128, 0, stream>>>(bufA, rowStart, col, w, dinv, b2, out, N);
}

// Round 2
// 354.992 us; speedup vs baseline: 1.1767x; 1.1767x over previous
//
#include <hip/hip_runtime.h>
#include <math.h>

#define D 128

// ---------------- degree / normalization ----------------

__global__ void init_cnt(int* __restrict__ cnt, int n) {
    int i = blockIdx.x * blockDim.x + threadIdx.x;
    if (i < n) cnt[i] = 0;
}

__global__ void count_deg(const int* __restrict__ dst, int* __restrict__ cnt, int e) {
    int i = blockIdx.x * blockDim.x + threadIdx.x;
    if (i < e) atomicAdd(&cnt[dst[i]], 1);
}

__global__ void compute_dinv(const int* __restrict__ cnt, float* __restrict__ dinv, int n) {
    int i = blockIdx.x * blockDim.x + threadIdx.x;
    // self-loop => deg = indeg + 1 >= 1, rsqrt always valid
    if (i < n) dinv[i] = rsqrtf((float)(cnt[i] + 1));
}

// ---------------- CSR build (scan + fill) ----------------

__global__ void scan_chunk(const int* __restrict__ cnt, int* __restrict__ rowStart,
                           int* __restrict__ chunkSum, int n) {
    __shared__ int sh[256];
    int tid = threadIdx.x;
    int i = blockIdx.x * 256 + tid;
    int v = (i < n) ? cnt[i] : 0;
    sh[tid] = v;
    __syncthreads();
    for (int o = 1; o < 256; o <<= 1) {
        int t = (tid >= o) ? sh[tid - o] : 0;
        __syncthreads();
        sh[tid] += t;
        __syncthreads();
    }
    if (i < n) rowStart[i] = sh[tid] - v;  // exclusive within chunk
    if (tid == 255) chunkSum[blockIdx.x] = sh[255];
}

__global__ void scan_tops(const int* __restrict__ chunkSum, int* __restrict__ chunkOff, int nb) {
    __shared__ int sh[256];
    int tid = threadIdx.x;
    int v = (tid < nb) ? chunkSum[tid] : 0;
    sh[tid] = v;
    __syncthreads();
    for (int o = 1; o < 256; o <<= 1) {
        int t = (tid >= o) ? sh[tid - o] : 0;
        __syncthreads();
        sh[tid] += t;
        __syncthreads();
    }
    if (tid < nb) chunkOff[tid] = sh[tid] - v;  // exclusive
}

__global__ void finalize_scan(int* __restrict__ rowStart, int* __restrict__ cursor,
                              const int* __restrict__ chunkOff, int n, int e) {
    int i = blockIdx.x * blockDim.x + threadIdx.x;
    if (i < n) {
        int r = rowStart[i] + chunkOff[i >> 8];
        rowStart[i] = r;
        cursor[i] = r;
    }
    if (i == 0) rowStart[n] = e;
}

__global__ void fill_csr(const int* __restrict__ src, const int* __restrict__ dst,
                         const float* __restrict__ dinv, int* __restrict__ cursor,
                         int* __restrict__ col, float* __restrict__ w, int e) {
    int i = blockIdx.x * blockDim.x + threadIdx.x;
    if (i < e) {
        int s = src[i], dd = dst[i];
        int p = atomicAdd(&cursor[dd], 1);
        col[p] = s;
        w[p] = dinv[s] * dinv[dd];
    }
}

// ---------------- dense transform: C[N,128] = A[N,128] @ W[128,128] ----------------

__global__ __launch_bounds__(256) void gemm_nd(const float* __restrict__ A,
                                               const float* __restrict__ Wm,
                                               float* __restrict__ C, int N) {
    __shared__ float As[32][68];
    __shared__ float Bs[32][128];

    const int tid = threadIdx.x;
    const int row0 = blockIdx.x * 64;
    const int tr = tid >> 5;
    const int tc = (tid & 31) << 2;

    float acc[8][4] = {};

    for (int k0 = 0; k0 < D; k0 += 32) {
#pragma unroll
        for (int i = 0; i < 2; ++i) {
            int idx = tid + i * 256;
            int m = idx >> 3;
            int kk = (idx & 7) << 2;
            float4 v = make_float4(0.f, 0.f, 0.f, 0.f);
            int gr = row0 + m;
            if (gr < N) v = *(const float4*)&A[(size_t)gr * D + k0 + kk];
            As[kk + 0][m] = v.x;
            As[kk + 1][m] = v.y;
            As[kk + 2][m] = v.z;
            As[kk + 3][m] = v.w;
        }
#pragma unroll
        for (int i = 0; i < 4; ++i) {
            int idx = tid + i * 256;
            int k = idx >> 5;
            int n = (idx & 31) << 2;
            *(float4*)&Bs[k][n] = *(const float4*)&Wm[(size_t)(k0 + k) * D + n];
        }
        __syncthreads();

#pragma unroll
        for (int k = 0; k < 32; ++k) {
            float4 b = *(float4*)&Bs[k][tc];
            float4 a0 = *(float4*)&As[k][tr * 8];
            float4 a1 = *(float4*)&As[k][tr * 8 + 4];
            float a[8] = {a0.x, a0.y, a0.z, a0.w, a1.x, a1.y, a1.z, a1.w};
            float bb[4] = {b.x, b.y, b.z, b.w};
#pragma unroll
            for (int r = 0; r < 8; ++r)
#pragma unroll
                for (int c = 0; c < 4; ++c)
                    acc[r][c] = fmaf(a[r], bb[c], acc[r][c]);
        }
        __syncthreads();
    }

#pragma unroll
    for (int r = 0; r < 8; ++r) {
        int gr = row0 + tr * 8 + r;
        if (gr < N) {
            float4 v = make_float4(acc[r][0], acc[r][1], acc[r][2], acc[r][3]);
            *(float4*)&C[(size_t)gr * D + tc] = v;
        }
    }
}

// ---------------- neighbor aggregation + bias + ELU ----------------
// wave-per-node: lane holds channels {2*lane, 2*lane+1} as float2, so one
// global_load_dwordx2 per wave fetches a full 512B row. Edge loop unrolled x4
// with 4 independent accumulators -> 4 row-gathers in flight per wave (MLP).

__global__ __launch_bounds__(256) void agg_elu(const float* __restrict__ h,
                                               const int* __restrict__ rowStart,
                                               const int* __restrict__ col,
                                               const float* __restrict__ w,
                                               const float* __restrict__ dinv,
                                               const float* __restrict__ bias,
                                               float* __restrict__ out, int n) {
    const int wid = threadIdx.x >> 6;            // wave id in block, 0..3
    const int lane = threadIdx.x & 63;           // 0..63
    const int node = blockIdx.x * 4 + wid;
    if (node >= n) return;

    const float2* __restrict__ h2 = (const float2*)h;

    float di = dinv[node];
    float2 self = h2[(size_t)node * 64 + lane];
    float sw = di * di;
    float2 a0 = make_float2(sw * self.x, sw * self.y);
    float2 a1 = make_float2(0.f, 0.f);
    float2 a2 = make_float2(0.f, 0.f);
    float2 a3 = make_float2(0.f, 0.f);

    const int s0 = rowStart[node];
    const int s1 = rowStart[node + 1];
    int i = s0;
    for (; i + 4 <= s1; i += 4) {
        int c0 = col[i + 0], c1 = col[i + 1], c2 = col[i + 2], c3 = col[i + 3];
        float w0 = w[i + 0], w1 = w[i + 1], w2 = w[i + 2], w3 = w[i + 3];
        float2 v0 = h2[(size_t)c0 * 64 + lane];
        float2 v1 = h2[(size_t)c1 * 64 + lane];
        float2 v2 = h2[(size_t)c2 * 64 + lane];
        float2 v3 = h2[(size_t)c3 * 64 + lane];
        a0.x = fmaf(w0, v0.x, a0.x); a0.y = fmaf(w0, v0.y, a0.y);
        a1.x = fmaf(w1, v1.x, a1.x); a1.y = fmaf(w1, v1.y, a1.y);
        a2.x = fmaf(w2, v2.x, a2.x); a2.y = fmaf(w2, v2.y, a2.y);
        a3.x = fmaf(w3, v3.x, a3.x); a3.y = fmaf(w3, v3.y, a3.y);
    }
    for (; i < s1; ++i) {
        int c = col[i];
        float ww = w[i];
        float2 v = h2[(size_t)c * 64 + lane];
        a0.x = fmaf(ww, v.x, a0.x); a0.y = fmaf(ww, v.y, a0.y);
    }

    float2 bv = ((const float2*)bias)[lane];
    float rx = a0.x + a1.x + a2.x + a3.x + bv.x;
    float ry = a0.y + a1.y + a2.y + a3.y + bv.y;
    rx = rx > 0.0f ? rx : expm1f(rx);
    ry = ry > 0.0f ? ry : expm1f(ry);
    ((float2*)out)[(size_t)node * 64 + lane] = make_float2(rx, ry);
}

// ---------------- launch ----------------

extern "C" void kernel_launch(void* const* d_in, const int* in_sizes, int n_in,
                              void* d_out, int out_size, void* d_ws, size_t ws_size,
                              hipStream_t stream) {
    const float* x  = (const float*)d_in[0];
    const int*   ei = (const int*)d_in[1];
    const float* W1 = (const float*)d_in[2];
    const float* b1 = (const float*)d_in[3];
    const float* W2 = (const float*)d_in[4];
    const float* b2 = (const float*)d_in[5];
    float* out = (float*)d_out;

    const int N = in_sizes[0] / D;
    const int E = in_sizes[1] / 2;
    const int* src = ei;
    const int* dst = ei + E;

    char* ws = (char*)d_ws;
    size_t off = 0;
    auto alloc = [&](size_t bytes) -> void* {
        void* p = ws + off;
        off = (off + bytes + 255) & ~(size_t)255;
        return p;
    };
    int*   cnt      = (int*)alloc((size_t)N * 4);
    int*   rowStart = (int*)alloc((size_t)(N + 1) * 4);
    int*   cursor   = (int*)alloc((size_t)N * 4);
    float* dinv     = (float*)alloc((size_t)N * 4);
    int*   chunkSum = (int*)alloc(256 * 4);
    int*   chunkOff = (int*)alloc(256 * 4);
    int*   col      = (int*)alloc((size_t)E * 4);
    float* w        = (float*)alloc((size_t)E * 4);
    float* bufA     = (float*)alloc((size_t)N * D * 4);
    (void)ws_size; (void)n_in; (void)out_size;

    const int nb256 = (N + 255) / 256;
    const int eb256 = (E + 255) / 256;

    init_cnt<<<nb256, 256, 0, stream>>>(cnt, N);
    count_deg<<<eb256, 256, 0, stream>>>(dst, cnt, E);
    compute_dinv<<<nb256, 256, 0, stream>>>(cnt, dinv, N);
    scan_chunk<<<nb256, 256, 0, stream>>>(cnt, rowStart, chunkSum, N);
    scan_tops<<<1, 256, 0, stream>>>(chunkSum, chunkOff, nb256);
    finalize_scan<<<nb256, 256, 0, stream>>>(rowStart, cursor, chunkOff, N, E);
    fill_csr<<<eb256, 256, 0, stream>>>(src, dst, dinv, cursor, col, w, E);

    const int gemmBlocks = (N + 63) / 64;
    const int aggBlocks = (N + 3) / 4;
    // layer 1
    gemm_nd<<<gemmBlocks, 256, 0, stream>>>(x, W1, bufA, N);
    agg_elu<<<aggBlocks, 256, 0, stream>>>(bufA, rowStart, col, w, dinv, b1, out, N);
    // layer 2
    gemm_nd<<<gemmBlocks, 256, 0, stream>>>(out, W2, bufA, N);
    agg_elu<<<aggBlocks, 256, 0, stream>>>(bufA, rowStart, col, w, dinv, b2, out, N);
}